// Round 1
// baseline (656.644 us; speedup 1.0000x reference)
//
#include <hip/hip_runtime.h>
#include <math.h>

#define B_ 4
#define S_ 4096
#define H_ 1024
#define NH 16
#define DH 64
#define CTX 128
#define CSTART (S_ - CTX)   // 3968

// ---------- gather last-128 rows per batch into contiguous Xs (512 x 1024) ----------
__global__ __launch_bounds__(256) void gather_x(const float* __restrict__ in,
                                                float* __restrict__ Xs) {
    int idx = blockIdx.x * 256 + threadIdx.x;   // float4 index, 512*256 total
    int m  = idx >> 8;                          // 0..511
    int c4 = idx & 255;
    int b = m >> 7, i = m & 127;
    const float4* src = (const float4*)(in + (size_t)(b * S_ + CSTART + i) * H_);
    float4* dst = (float4*)(Xs + (size_t)m * H_);
    dst[c4] = src[c4];
}

// ---------- generic fp32 GEMM: C[M,N] = A[M,K] * B[N,K]^T, row-major, ldc given ----------
#define BM 64
#define BN 64
#define BK 16

__global__ __launch_bounds__(256) void gemm_nt(const float* __restrict__ A,
                                               const float* __restrict__ Bm,
                                               float* __restrict__ C,
                                               int K, int ldc) {
    __shared__ float As[BK][BM + 1];
    __shared__ float Bs[BK][BN + 1];
    int tid = threadIdx.x;
    int tx = tid & 15;    // -> n
    int ty = tid >> 4;    // -> m
    int m0 = blockIdx.y * BM;
    int n0 = blockIdx.x * BN;
    float acc[4][4] = {};
    for (int k0 = 0; k0 < K; k0 += BK) {
        #pragma unroll
        for (int i = 0; i < 4; i++) {
            int idx = tid + i * 256;            // 0..1023
            int kk = idx & 15;
            int mm = idx >> 4;
            As[kk][mm] = A[(size_t)(m0 + mm) * K + k0 + kk];
        }
        #pragma unroll
        for (int i = 0; i < 4; i++) {
            int idx = tid + i * 256;
            int kk = idx & 15;
            int nn = idx >> 4;
            Bs[kk][nn] = Bm[(size_t)(n0 + nn) * K + k0 + kk];
        }
        __syncthreads();
        #pragma unroll
        for (int kk = 0; kk < BK; kk++) {
            float a[4], bv[4];
            #pragma unroll
            for (int i = 0; i < 4; i++) a[i] = As[kk][ty + 16 * i];
            #pragma unroll
            for (int j = 0; j < 4; j++) bv[j] = Bs[kk][tx + 16 * j];
            #pragma unroll
            for (int i = 0; i < 4; i++)
                #pragma unroll
                for (int j = 0; j < 4; j++)
                    acc[i][j] += a[i] * bv[j];
        }
        __syncthreads();
    }
    #pragma unroll
    for (int i = 0; i < 4; i++)
        #pragma unroll
        for (int j = 0; j < 4; j++)
            C[(size_t)(m0 + ty + 16 * i) * ldc + (n0 + tx + 16 * j)] = acc[i][j];
}

// ---------- attention over the last 128 positions, one block per (b,h) ----------
// QKV layout: row (b*128+s), cols [0,1024)=Q, [1024,2048)=K, [2048,3072)=V; n = h*64+d
__global__ __launch_bounds__(128) void attn(const float* __restrict__ QKV,
                                            const int* __restrict__ amask,
                                            float* __restrict__ AO) {
    int b = blockIdx.x >> 4;
    int h = blockIdx.x & 15;
    __shared__ float Ks[CTX][DH];   // 32 KB
    __shared__ float Vs[CTX][DH];   // 32 KB
    int tid = threadIdx.x;
    for (int idx = tid; idx < CTX * DH; idx += 128) {
        int c = idx >> 6, d = idx & 63;
        size_t row = (size_t)(b * CTX + c) * 3072;
        Ks[c][d] = QKV[row + 1024 + h * 64 + d];
        Vs[c][d] = QKV[row + 2048 + h * 64 + d];
    }
    __syncthreads();
    int q = tid;   // 0..127  (query local position)
    // load this thread's Q row from global (contiguous 256B per thread)
    float qr[DH];
    {
        const float4* qsrc = (const float4*)(QKV + (size_t)(b * CTX + q) * 3072 + h * 64);
        #pragma unroll
        for (int i = 0; i < DH / 4; i++) {
            float4 v = qsrc[i];
            qr[4 * i + 0] = v.x; qr[4 * i + 1] = v.y;
            qr[4 * i + 2] = v.z; qr[4 * i + 3] = v.w;
        }
    }
    const int* mrow = amask + b * S_ + CSTART;
    float m = -INFINITY, l = 0.f;
    float acc[DH];
    #pragma unroll
    for (int d = 0; d < DH; d++) acc[d] = 0.f;
    for (int c = 0; c <= q; c++) {           // causal within the window
        if (mrow[c] == 0) continue;          // padding mask (all-ones in practice)
        float s = 0.f;
        #pragma unroll
        for (int d = 0; d < DH; d++) s += qr[d] * Ks[c][d];
        s *= 0.125f;                          // 1/sqrt(64)
        float mn = fmaxf(m, s);
        float alpha = __expf(m - mn);         // 0 on first iteration (m=-inf)
        float p = __expf(s - mn);
        l = l * alpha + p;
        #pragma unroll
        for (int d = 0; d < DH; d++) acc[d] = acc[d] * alpha + p * Vs[c][d];
        m = mn;
    }
    float inv = 1.f / l;
    float* orow = AO + (size_t)(b * CTX + q) * 1024 + h * 64;
    #pragma unroll
    for (int d = 0; d < DH; d++) orow[d] = acc[d] * inv;
}

// ---------- r[b] = V_row(b, ctx pos 0) @ Wo^T  (the broadcast row) ----------
__global__ __launch_bounds__(256) void calc_r(const float* __restrict__ QKV,
                                              const float* __restrict__ Wo,
                                              float* __restrict__ r) {
    int b = blockIdx.x;
    __shared__ float v0[H_];
    int tid = threadIdx.x;
    for (int i = tid; i < H_; i += 256)
        v0[i] = QKV[(size_t)(b * CTX) * 3072 + 2048 + i];
    __syncthreads();
    #pragma unroll
    for (int j = 0; j < 4; j++) {
        int n = tid + 256 * j;
        const float* wrow = Wo + (size_t)n * H_;
        float a0 = 0, a1 = 0, a2 = 0, a3 = 0;
        for (int k = 0; k < H_; k += 4) {
            a0 += v0[k + 0] * wrow[k + 0];
            a1 += v0[k + 1] * wrow[k + 1];
            a2 += v0[k + 2] * wrow[k + 2];
            a3 += v0[k + 3] * wrow[k + 3];
        }
        r[b * H_ + n] = a0 + a1 + a2 + a3;
    }
}

// ---------- final output assembly: broadcast rows + last-128 rows ----------
__global__ __launch_bounds__(256) void write_out(const float* __restrict__ OUTL,
                                                 const float* __restrict__ r,
                                                 float* __restrict__ out) {
    size_t idx = (size_t)blockIdx.x * 256 + threadIdx.x;   // float4 index, 4.19M total
    int row = (int)(idx >> 8);     // 0..16383  (b*4096 + p)
    int c4  = (int)(idx & 255);
    int b = row >> 12;
    int p = row & 4095;
    const float4* src;
    if (p < CSTART) src = (const float4*)(r + (size_t)b * H_);
    else            src = (const float4*)(OUTL + (size_t)(b * CTX + (p - CSTART)) * H_);
    ((float4*)out)[idx] = src[c4];
}

extern "C" void kernel_launch(void* const* d_in, const int* in_sizes, int n_in,
                              void* d_out, int out_size, void* d_ws, size_t ws_size,
                              hipStream_t stream) {
    const float* inputs = (const float*)d_in[0];
    const int*   amask  = (const int*)d_in[1];
    const float* Wq     = (const float*)d_in[2];
    const float* Wk     = (const float*)d_in[3];
    const float* Wv     = (const float*)d_in[4];
    const float* Wo     = (const float*)d_in[5];
    float* out = (float*)d_out;

    float* ws   = (float*)d_ws;
    float* Xs   = ws;                     // 512*1024
    float* QKV  = Xs + 512 * 1024;        // 512*3072
    float* AO   = QKV + 512 * 3072;       // 512*1024
    float* OUTL = AO + 512 * 1024;        // 512*1024
    float* r    = OUTL + 512 * 1024;      // 4*1024    (~12.6 MB total)

    gather_x<<<512, 256, 0, stream>>>(inputs, Xs);

    dim3 g1(1024 / BN, 512 / BM);
    gemm_nt<<<g1, 256, 0, stream>>>(Xs, Wq, QKV + 0,    1024, 3072);
    gemm_nt<<<g1, 256, 0, stream>>>(Xs, Wk, QKV + 1024, 1024, 3072);
    gemm_nt<<<g1, 256, 0, stream>>>(Xs, Wv, QKV + 2048, 1024, 3072);

    attn<<<64, 128, 0, stream>>>(QKV, amask, AO);
    calc_r<<<4, 256, 0, stream>>>(QKV, Wo, r);

    gemm_nt<<<g1, 256, 0, stream>>>(AO, Wo, OUTL, 1024, 1024);

    write_out<<<16384, 256, 0, stream>>>(OUTL, r, out);
}

// Round 2
// 250.125 us; speedup vs baseline: 2.6253x; 2.6253x over previous
//
#include <hip/hip_runtime.h>
#include <math.h>

#define B_ 4
#define S_ 4096
#define H_ 1024
#define NH 16
#define DH 64
#define CTX 128
#define CSTART (S_ - CTX)   // 3968
#define KDIM 1024

typedef __attribute__((ext_vector_type(8))) short short8;
typedef __attribute__((ext_vector_type(4))) float floatx4;

__device__ inline unsigned short f2bf(float x) {
    union { float f; unsigned u; } v; v.f = x;
    unsigned r = v.u + 0x7fffu + ((v.u >> 16) & 1u);   // round-to-nearest-even
    return (unsigned short)(r >> 16);
}

#define GLOAD_LDS16(g, l) \
    __builtin_amdgcn_global_load_lds((__attribute__((address_space(1))) const void*)(g), \
                                     (__attribute__((address_space(3))) void*)(l), 16, 0, 0)

// ---------- gather last-128 rows per batch -> bf16 Xs (512 x 1024) ----------
__global__ __launch_bounds__(256) void gather_x_bf16(const float* __restrict__ in,
                                                     unsigned short* __restrict__ Xs) {
    int idx = blockIdx.x * 256 + threadIdx.x;     // 65536 threads, 8 elems each
    int e = idx * 8;
    int m = e >> 10;            // 0..511
    int col = e & 1023;
    int b = m >> 7, i = m & 127;
    const float4* s4 = (const float4*)(in + (size_t)(b * S_ + CSTART + i) * H_ + col);
    float4 x = s4[0], y = s4[1];
    union { unsigned short us[8]; uint4 u4; } p;
    p.us[0]=f2bf(x.x); p.us[1]=f2bf(x.y); p.us[2]=f2bf(x.z); p.us[3]=f2bf(x.w);
    p.us[4]=f2bf(y.x); p.us[5]=f2bf(y.y); p.us[6]=f2bf(y.z); p.us[7]=f2bf(y.w);
    *(uint4*)(Xs + e) = p.u4;
}

// ---------- convert Wq|Wk|Wv|Wo -> stacked bf16 Wbf[4096][1024] ----------
__global__ __launch_bounds__(256) void conv_w(const float* __restrict__ Wq, const float* __restrict__ Wk,
                                              const float* __restrict__ Wv, const float* __restrict__ Wo,
                                              unsigned short* __restrict__ Wbf) {
    size_t idx = (size_t)blockIdx.x * 256 + threadIdx.x;   // 524288 threads
    size_t e = idx * 8;
    int wsel = (int)(e >> 20);
    size_t off = e & 1048575;
    const float* src = wsel == 0 ? Wq : wsel == 1 ? Wk : wsel == 2 ? Wv : Wo;
    const float4* s4 = (const float4*)(src + off);
    float4 x = s4[0], y = s4[1];
    union { unsigned short us[8]; uint4 u4; } p;
    p.us[0]=f2bf(x.x); p.us[1]=f2bf(x.y); p.us[2]=f2bf(x.z); p.us[3]=f2bf(x.w);
    p.us[4]=f2bf(y.x); p.us[5]=f2bf(y.y); p.us[6]=f2bf(y.z); p.us[7]=f2bf(y.w);
    *(uint4*)(Wbf + e) = p.u4;
}

// ---------- bf16 MFMA GEMM: C[512,N] = A[512,1024] @ W[N,1024]^T, fp32 out ----------
// 64x64 tile, 4 waves in 2x2, each wave 32x32 via 4x mfma_f32_16x16x32_bf16.
// LDS chunk-position XOR-swizzled by (row>>1)&3 so frag ds_read_b128 is conflict-free
// while global_load_lds keeps its wave-uniform-base + lane*16 layout.
__global__ __launch_bounds__(256) void gemm_bf16(const unsigned short* __restrict__ A,
                                                 const unsigned short* __restrict__ W,
                                                 float* __restrict__ C, int ldc) {
    __shared__ unsigned short As[64][32];
    __shared__ unsigned short Bs[64][32];
    int tid = threadIdx.x;
    int lane = tid & 63, w = tid >> 6;
    int m0 = blockIdx.y * 64, n0 = blockIdx.x * 64;
    // staging: lane l of wave w fills LDS row sr, chunk position scp (hardware layout)
    int sr  = w * 16 + (lane >> 2);
    int scp = lane & 3;
    int sgc = scp ^ ((sr >> 1) & 3);          // which global chunk lands here
    const unsigned short* ga = A + (size_t)(m0 + sr) * KDIM + sgc * 8;
    const unsigned short* gb = W + (size_t)(n0 + sr) * KDIM + sgc * 8;
    unsigned short* la = &As[sr][scp * 8];
    unsigned short* lb = &Bs[sr][scp * 8];
    // fragments
    int fm = lane & 15, q = lane >> 4;
    int wr = w >> 1, wc = w & 1;
    int ma0 = wr * 32, na0 = wc * 32;
    floatx4 acc[2][2] = {};
    for (int k0 = 0; k0 < KDIM; k0 += 32) {
        GLOAD_LDS16(ga + k0, la);
        GLOAD_LDS16(gb + k0, lb);
        __syncthreads();
        short8 af[2], bfr[2];
        #pragma unroll
        for (int t = 0; t < 2; t++) {
            int m = ma0 + t * 16 + fm;
            af[t]  = *(const short8*)&As[m][(q ^ ((m >> 1) & 3)) * 8];
            int n = na0 + t * 16 + fm;
            bfr[t] = *(const short8*)&Bs[n][(q ^ ((n >> 1) & 3)) * 8];
        }
        #pragma unroll
        for (int i = 0; i < 2; i++)
            #pragma unroll
            for (int j = 0; j < 2; j++)
                acc[i][j] = __builtin_amdgcn_mfma_f32_16x16x32_bf16(af[i], bfr[j], acc[i][j], 0, 0, 0);
        __syncthreads();
    }
    // C/D layout: col = lane&15, row = quad*4 + reg
    #pragma unroll
    for (int i = 0; i < 2; i++)
        #pragma unroll
        for (int j = 0; j < 2; j++) {
            int row = m0 + ma0 + i * 16 + q * 4;
            int col = n0 + na0 + j * 16 + fm;
            #pragma unroll
            for (int t = 0; t < 4; t++)
                C[(size_t)(row + t) * ldc + col] = acc[i][j][t];
        }
}

// ---------- attention over last 128 positions, one block per (b,h); AO in bf16 ----------
__global__ __launch_bounds__(128) void attn(const float* __restrict__ QKV,
                                            const int* __restrict__ amask,
                                            unsigned short* __restrict__ AO) {
    int b = blockIdx.x >> 4;
    int h = blockIdx.x & 15;
    __shared__ float Ks[CTX][DH];
    __shared__ float Vs[CTX][DH];
    int tid = threadIdx.x;
    for (int idx = tid; idx < CTX * DH; idx += 128) {
        int c = idx >> 6, d = idx & 63;
        size_t row = (size_t)(b * CTX + c) * 3072;
        Ks[c][d] = QKV[row + 1024 + h * 64 + d];
        Vs[c][d] = QKV[row + 2048 + h * 64 + d];
    }
    __syncthreads();
    int qq = tid;
    float qr[DH];
    {
        const float4* qsrc = (const float4*)(QKV + (size_t)(b * CTX + qq) * 3072 + h * 64);
        #pragma unroll
        for (int i = 0; i < DH / 4; i++) {
            float4 v = qsrc[i];
            qr[4*i+0]=v.x; qr[4*i+1]=v.y; qr[4*i+2]=v.z; qr[4*i+3]=v.w;
        }
    }
    const int* mrow = amask + b * S_ + CSTART;
    float m = -INFINITY, l = 0.f;
    float acc[DH];
    #pragma unroll
    for (int d = 0; d < DH; d++) acc[d] = 0.f;
    for (int c = 0; c <= qq; c++) {
        if (mrow[c] == 0) continue;
        float s = 0.f;
        #pragma unroll
        for (int d = 0; d < DH; d++) s += qr[d] * Ks[c][d];
        s *= 0.125f;
        float mn = fmaxf(m, s);
        float alpha = __expf(m - mn);
        float p = __expf(s - mn);
        l = l * alpha + p;
        #pragma unroll
        for (int d = 0; d < DH; d++) acc[d] = acc[d] * alpha + p * Vs[c][d];
        m = mn;
    }
    float inv = 1.f / l;
    unsigned short* orow = AO + (size_t)(b * CTX + qq) * 1024 + h * 64;
    #pragma unroll
    for (int d = 0; d < DH; d++) orow[d] = f2bf(acc[d] * inv);
}

// ---------- final output: broadcast OUTL row (b*128) for p<3968, else OUTL row ----------
__global__ __launch_bounds__(256) void write_out(const float* __restrict__ OUTL,
                                                 float* __restrict__ out) {
    size_t idx = (size_t)blockIdx.x * 256 + threadIdx.x;   // float4 index
    int row = (int)(idx >> 8);
    int c4  = (int)(idx & 255);
    int b = row >> 12;
    int p = row & 4095;
    int lrow = (p < CSTART) ? 0 : (p - CSTART);            // row 0 == q=0 == broadcast row
    const float4* src = (const float4*)(OUTL + (size_t)(b * CTX + lrow) * H_);
    ((float4*)out)[idx] = src[c4];
}

extern "C" void kernel_launch(void* const* d_in, const int* in_sizes, int n_in,
                              void* d_out, int out_size, void* d_ws, size_t ws_size,
                              hipStream_t stream) {
    const float* inputs = (const float*)d_in[0];
    const int*   amask  = (const int*)d_in[1];
    const float* Wq     = (const float*)d_in[2];
    const float* Wk     = (const float*)d_in[3];
    const float* Wv     = (const float*)d_in[4];
    const float* Wo     = (const float*)d_in[5];
    float* out = (float*)d_out;

    char* ws = (char*)d_ws;
    unsigned short* Xs   = (unsigned short*)(ws);                     // 1 MB
    unsigned short* Wbf  = (unsigned short*)(ws + (1u << 20));        // 8 MB  (Wq|Wk|Wv|Wo rows 0..4095)
    float*          QKV  = (float*)(ws + (9u << 20));                 // 6 MB  [512][3072]
    unsigned short* AObf = (unsigned short*)(ws + (15u << 20));       // 1 MB  [512][1024]
    float*          OUTL = (float*)(ws + (16u << 20));                // 2 MB  [512][1024]

    gather_x_bf16<<<256, 256, 0, stream>>>(inputs, Xs);
    conv_w<<<2048, 256, 0, stream>>>(Wq, Wk, Wv, Wo, Wbf);

    // Fused QKV GEMM: N = 3072 against stacked [Wq|Wk|Wv]
    dim3 gq(3072 / 64, 512 / 64);
    gemm_bf16<<<gq, 256, 0, stream>>>(Xs, Wbf, QKV, 3072);

    attn<<<64, 128, 0, stream>>>(QKV, amask, AObf);

    // OUTL = AO @ Wo^T  (Wo rows are Wbf rows 3072..4095)
    dim3 go(1024 / 64, 512 / 64);
    gemm_bf16<<<go, 256, 0, stream>>>(AObf, Wbf + (size_t)3072 * 1024, OUTL, 1024);

    write_out<<<16384, 256, 0, stream>>>(OUTL, out);
}

// Round 3
// 169.005 us; speedup vs baseline: 3.8854x; 1.4800x over previous
//
#include <hip/hip_runtime.h>
#include <math.h>

#define B_ 4
#define S_ 4096
#define H_ 1024
#define NH 16
#define DH 64
#define CTX 128
#define CSTART (S_ - CTX)   // 3968
#define KDIM 1024

typedef __attribute__((ext_vector_type(8))) short short8;
typedef __attribute__((ext_vector_type(4))) float floatx4;

__device__ inline unsigned short f2bf(float x) {
    union { float f; unsigned u; } v; v.f = x;
    unsigned r = v.u + 0x7fffu + ((v.u >> 16) & 1u);   // round-to-nearest-even
    return (unsigned short)(r >> 16);
}

#define GLOAD_LDS16(g, l) \
    __builtin_amdgcn_global_load_lds((__attribute__((address_space(1))) const void*)(g), \
                                     (__attribute__((address_space(3))) void*)(l), 16, 0, 0)

// ---------- gather last-128 rows per batch -> bf16 Xs (512 x 1024) ----------
__global__ __launch_bounds__(256) void gather_x_bf16(const float* __restrict__ in,
                                                     unsigned short* __restrict__ Xs) {
    int idx = blockIdx.x * 256 + threadIdx.x;
    int e = idx * 8;
    int m = e >> 10;
    int col = e & 1023;
    int b = m >> 7, i = m & 127;
    const float4* s4 = (const float4*)(in + (size_t)(b * S_ + CSTART + i) * H_ + col);
    float4 x = s4[0], y = s4[1];
    union { unsigned short us[8]; uint4 u4; } p;
    p.us[0]=f2bf(x.x); p.us[1]=f2bf(x.y); p.us[2]=f2bf(x.z); p.us[3]=f2bf(x.w);
    p.us[4]=f2bf(y.x); p.us[5]=f2bf(y.y); p.us[6]=f2bf(y.z); p.us[7]=f2bf(y.w);
    *(uint4*)(Xs + e) = p.u4;
}

// ---------- convert Wq|Wk|Wv|Wo -> stacked bf16 Wbf[4096][1024] ----------
__global__ __launch_bounds__(256) void conv_w(const float* __restrict__ Wq, const float* __restrict__ Wk,
                                              const float* __restrict__ Wv, const float* __restrict__ Wo,
                                              unsigned short* __restrict__ Wbf) {
    size_t idx = (size_t)blockIdx.x * 256 + threadIdx.x;
    size_t e = idx * 8;
    int wsel = (int)(e >> 20);
    size_t off = e & 1048575;
    const float* src = wsel == 0 ? Wq : wsel == 1 ? Wk : wsel == 2 ? Wv : Wo;
    const float4* s4 = (const float4*)(src + off);
    float4 x = s4[0], y = s4[1];
    union { unsigned short us[8]; uint4 u4; } p;
    p.us[0]=f2bf(x.x); p.us[1]=f2bf(x.y); p.us[2]=f2bf(x.z); p.us[3]=f2bf(x.w);
    p.us[4]=f2bf(y.x); p.us[5]=f2bf(y.y); p.us[6]=f2bf(y.z); p.us[7]=f2bf(y.w);
    *(uint4*)(Wbf + e) = p.u4;
}

// ---------- bf16 MFMA GEMM: C[512,N] = A[512,1024] @ W[N,1024]^T, fp32 out ----------
__global__ __launch_bounds__(256) void gemm_bf16(const unsigned short* __restrict__ A,
                                                 const unsigned short* __restrict__ W,
                                                 float* __restrict__ C, int ldc) {
    __shared__ unsigned short As[64][32];
    __shared__ unsigned short Bs[64][32];
    int tid = threadIdx.x;
    int lane = tid & 63, w = tid >> 6;
    int m0 = blockIdx.y * 64, n0 = blockIdx.x * 64;
    int sr  = w * 16 + (lane >> 2);
    int scp = lane & 3;
    int sgc = scp ^ ((sr >> 1) & 3);
    const unsigned short* ga = A + (size_t)(m0 + sr) * KDIM + sgc * 8;
    const unsigned short* gb = W + (size_t)(n0 + sr) * KDIM + sgc * 8;
    unsigned short* la = &As[sr][scp * 8];
    unsigned short* lb = &Bs[sr][scp * 8];
    int fm = lane & 15, q = lane >> 4;
    int wr = w >> 1, wc = w & 1;
    int ma0 = wr * 32, na0 = wc * 32;
    floatx4 acc[2][2] = {};
    for (int k0 = 0; k0 < KDIM; k0 += 32) {
        GLOAD_LDS16(ga + k0, la);
        GLOAD_LDS16(gb + k0, lb);
        __syncthreads();
        short8 af[2], bfr[2];
        #pragma unroll
        for (int t = 0; t < 2; t++) {
            int m = ma0 + t * 16 + fm;
            af[t]  = *(const short8*)&As[m][(q ^ ((m >> 1) & 3)) * 8];
            int n = na0 + t * 16 + fm;
            bfr[t] = *(const short8*)&Bs[n][(q ^ ((n >> 1) & 3)) * 8];
        }
        #pragma unroll
        for (int i = 0; i < 2; i++)
            #pragma unroll
            for (int j = 0; j < 2; j++)
                acc[i][j] = __builtin_amdgcn_mfma_f32_16x16x32_bf16(af[i], bfr[j], acc[i][j], 0, 0, 0);
        __syncthreads();
    }
    #pragma unroll
    for (int i = 0; i < 2; i++)
        #pragma unroll
        for (int j = 0; j < 2; j++) {
            int row = m0 + ma0 + i * 16 + q * 4;
            int col = n0 + na0 + j * 16 + fm;
            #pragma unroll
            for (int t = 0; t < 4; t++)
                C[(size_t)(row + t) * ldc + col] = acc[i][j][t];
        }
}

// ---------- attention: one wave per query; block = (b, h, 16-query chunk) ----------
// Phase 1: lanes = context positions (c=lane, c=lane+64), wave-softmax via shfl_xor.
// Phase 2: lanes = head dims, loop over c.  K/V padded to 65 -> bank (c+d)%32, 2-way free.
__global__ __launch_bounds__(1024) void attn(const float* __restrict__ QKV,
                                             const int* __restrict__ amask,
                                             unsigned short* __restrict__ AO) {
    int qc = blockIdx.x;       // 0..7
    int h  = blockIdx.y;       // 0..15
    int b  = blockIdx.z;       // 0..3
    int cmax = qc * 16 + 16;   // causal: this block's queries see c < cmax
    __shared__ float Ks[CTX][DH + 1];
    __shared__ float Vs[CTX][DH + 1];
    __shared__ float Qs[16][DH];
    __shared__ float Pw[16][CTX];
    int tid = threadIdx.x;
    for (int idx = tid; idx < cmax * 16; idx += 1024) {
        int c = idx >> 4, f4 = idx & 15;
        size_t row = (size_t)(b * CTX + c) * 3072 + h * 64 + f4 * 4;
        float4 kv = *(const float4*)(QKV + row + 1024);
        float4 vv = *(const float4*)(QKV + row + 2048);
        Ks[c][f4*4+0]=kv.x; Ks[c][f4*4+1]=kv.y; Ks[c][f4*4+2]=kv.z; Ks[c][f4*4+3]=kv.w;
        Vs[c][f4*4+0]=vv.x; Vs[c][f4*4+1]=vv.y; Vs[c][f4*4+2]=vv.z; Vs[c][f4*4+3]=vv.w;
    }
    if (tid < 256) {
        int qr = tid >> 4, f4 = tid & 15;
        size_t row = (size_t)(b * CTX + qc * 16 + qr) * 3072 + h * 64;
        *(float4*)&Qs[qr][f4 * 4] = *(const float4*)(QKV + row + f4 * 4);
    }
    __syncthreads();
    int w = tid >> 6, lane = tid & 63;
    int q = qc * 16 + w;                       // this wave's query (local pos)
    const int* mrow = amask + b * S_ + CSTART;
    // --- scores: lane handles c=lane and c=lane+64 ---
    float s0 = 0.f;
    #pragma unroll
    for (int d = 0; d < DH; d++) s0 += Qs[w][d] * Ks[lane][d];
    s0 = ((lane <= q) && (mrow[lane] != 0)) ? s0 * 0.125f : -INFINITY;
    float s1 = -INFINITY;
    if (q >= 64) {                              // wave-uniform branch
        float t = 0.f;
        #pragma unroll
        for (int d = 0; d < DH; d++) t += Qs[w][d] * Ks[lane + 64][d];
        s1 = ((lane + 64 <= q) && (mrow[lane + 64] != 0)) ? t * 0.125f : -INFINITY;
    }
    float sm = fmaxf(s0, s1);
    #pragma unroll
    for (int off = 32; off >= 1; off >>= 1) sm = fmaxf(sm, __shfl_xor(sm, off, 64));
    float p0 = __expf(s0 - sm);
    float p1 = (q >= 64) ? __expf(s1 - sm) : 0.f;
    float ls = p0 + p1;
    #pragma unroll
    for (int off = 32; off >= 1; off >>= 1) ls += __shfl_xor(ls, off, 64);
    Pw[w][lane] = p0;
    Pw[w][lane + 64] = p1;
    __syncthreads();
    // --- PV: lane = head dim, loop c (2 partial accumulators to pipeline) ---
    float inv = 1.f / ls;
    float av0 = 0.f, av1 = 0.f;
    int c = 0;
    for (; c + 1 <= q; c += 2) {
        av0 += Pw[w][c]     * Vs[c][lane];
        av1 += Pw[w][c + 1] * Vs[c + 1][lane];
    }
    if (c <= q) av0 += Pw[w][c] * Vs[c][lane];
    float o = (av0 + av1) * inv;
    AO[(size_t)(b * CTX + q) * 1024 + h * 64 + lane] = f2bf(o);
}

// ---------- final output: broadcast OUTL row (b*128) for p<3968, else OUTL row ----------
__global__ __launch_bounds__(256) void write_out(const float* __restrict__ OUTL,
                                                 float* __restrict__ out) {
    size_t idx = (size_t)blockIdx.x * 256 + threadIdx.x;
    int row = (int)(idx >> 8);
    int c4  = (int)(idx & 255);
    int b = row >> 12;
    int p = row & 4095;
    int lrow = (p < CSTART) ? 0 : (p - CSTART);
    const float4* src = (const float4*)(OUTL + (size_t)(b * CTX + lrow) * H_);
    ((float4*)out)[idx] = src[c4];
}

extern "C" void kernel_launch(void* const* d_in, const int* in_sizes, int n_in,
                              void* d_out, int out_size, void* d_ws, size_t ws_size,
                              hipStream_t stream) {
    const float* inputs = (const float*)d_in[0];
    const int*   amask  = (const int*)d_in[1];
    const float* Wq     = (const float*)d_in[2];
    const float* Wk     = (const float*)d_in[3];
    const float* Wv     = (const float*)d_in[4];
    const float* Wo     = (const float*)d_in[5];
    float* out = (float*)d_out;

    char* ws = (char*)d_ws;
    unsigned short* Xs   = (unsigned short*)(ws);                     // 1 MB
    unsigned short* Wbf  = (unsigned short*)(ws + (1u << 20));        // 8 MB
    float*          QKV  = (float*)(ws + (9u << 20));                 // 6 MB  [512][3072]
    unsigned short* AObf = (unsigned short*)(ws + (15u << 20));       // 1 MB  [512][1024]
    float*          OUTL = (float*)(ws + (16u << 20));                // 2 MB  [512][1024]

    gather_x_bf16<<<256, 256, 0, stream>>>(inputs, Xs);
    conv_w<<<2048, 256, 0, stream>>>(Wq, Wk, Wv, Wo, Wbf);

    dim3 gq(3072 / 64, 512 / 64);
    gemm_bf16<<<gq, 256, 0, stream>>>(Xs, Wbf, QKV, 3072);

    dim3 ga(8, 16, 4);
    attn<<<ga, 1024, 0, stream>>>(QKV, amask, AObf);

    dim3 go(1024 / 64, 512 / 64);
    gemm_bf16<<<go, 256, 0, stream>>>(AObf, Wbf + (size_t)3072 * 1024, OUTL, 1024);

    write_out<<<16384, 256, 0, stream>>>(OUTL, out);
}

// Round 4
// 156.617 us; speedup vs baseline: 4.1927x; 1.0791x over previous
//
#include <hip/hip_runtime.h>
#include <math.h>

#define B_ 4
#define S_ 4096
#define H_ 1024
#define NH 16
#define DH 64
#define CTX 128
#define CSTART (S_ - CTX)   // 3968
#define KDIM 1024

typedef __attribute__((ext_vector_type(8))) short short8;
typedef __attribute__((ext_vector_type(4))) float floatx4;
typedef unsigned short ushort_t;

__device__ inline unsigned short f2bf(float x) {
    union { float f; unsigned u; } v; v.f = x;
    unsigned r = v.u + 0x7fffu + ((v.u >> 16) & 1u);   // RNE
    return (unsigned short)(r >> 16);
}

__device__ inline uint4 pack8(float4 a, float4 b) {
    union { unsigned short us[8]; uint4 u4; } p;
    p.us[0]=f2bf(a.x); p.us[1]=f2bf(a.y); p.us[2]=f2bf(a.z); p.us[3]=f2bf(a.w);
    p.us[4]=f2bf(b.x); p.us[5]=f2bf(b.y); p.us[6]=f2bf(b.z); p.us[7]=f2bf(b.w);
    return p.u4;
}

#define GLOAD_LDS16(g, l) \
    __builtin_amdgcn_global_load_lds((__attribute__((address_space(1))) const void*)(g), \
                                     (__attribute__((address_space(3))) void*)(l), 16, 0, 0)

// ---------- prep: conv weights (blocks 0..2047) + gather x slice (2048..2303) ----------
__global__ __launch_bounds__(256) void prep(const float* __restrict__ in,
                                            const float* __restrict__ Wq, const float* __restrict__ Wk,
                                            const float* __restrict__ Wv, const float* __restrict__ Wo,
                                            ushort_t* __restrict__ Wbf, ushort_t* __restrict__ Xs) {
    int bx = blockIdx.x;
    if (bx < 2048) {
        size_t idx = (size_t)bx * 256 + threadIdx.x;
        size_t e = idx * 8;
        int wsel = (int)(e >> 20);
        size_t off = e & 1048575;
        const float* src = wsel == 0 ? Wq : wsel == 1 ? Wk : wsel == 2 ? Wv : Wo;
        const float4* s4 = (const float4*)(src + off);
        *(uint4*)(Wbf + e) = pack8(s4[0], s4[1]);
    } else {
        int idx = (bx - 2048) * 256 + threadIdx.x;
        int e = idx * 8;
        int m = e >> 10;
        int col = e & 1023;
        int b = m >> 7, i = m & 127;
        const float4* s4 = (const float4*)(in + (size_t)(b * S_ + CSTART + i) * H_ + col);
        *(uint4*)(Xs + e) = pack8(s4[0], s4[1]);
    }
}

// ---------- bf16 MFMA GEMM, BK=64: C[512,N] = A[512,1024] @ W[N,1024]^T ----------
// LDS 64x64 bf16 tiles, chunk-swizzle p = g ^ (row&7): staging stays
// wave-uniform-base+lane*16, frag ds_read_b128 is 2-way (free).
__global__ __launch_bounds__(256) void gemm_bf16(const ushort_t* __restrict__ A,
                                                 const ushort_t* __restrict__ W,
                                                 float* __restrict__ C, int ldc) {
    __shared__ ushort_t As[64][64];
    __shared__ ushort_t Bs[64][64];
    int tid = threadIdx.x;
    int lane = tid & 63, w = tid >> 6;
    int m0 = blockIdx.y * 64, n0 = blockIdx.x * 64;
    int f0 = tid, f1 = tid + 256;
    int r0 = f0 >> 3, g0 = (f0 & 7) ^ (r0 & 7);
    int r1 = f1 >> 3, g1 = (f1 & 7) ^ (r1 & 7);
    const ushort_t* ga0 = A + (size_t)(m0 + r0) * KDIM + g0 * 8;
    const ushort_t* ga1 = A + (size_t)(m0 + r1) * KDIM + g1 * 8;
    const ushort_t* gb0 = W + (size_t)(n0 + r0) * KDIM + g0 * 8;
    const ushort_t* gb1 = W + (size_t)(n0 + r1) * KDIM + g1 * 8;
    char* la0 = (char*)As + f0 * 16;
    char* la1 = (char*)As + f1 * 16;
    char* lb0 = (char*)Bs + f0 * 16;
    char* lb1 = (char*)Bs + f1 * 16;
    int fm = lane & 15, q = lane >> 4;
    int wr = w >> 1, wc = w & 1;
    int ma0 = wr * 32, na0 = wc * 32;
    floatx4 acc[2][2] = {};
    for (int k0 = 0; k0 < KDIM; k0 += 64) {
        GLOAD_LDS16(ga0 + k0, la0);
        GLOAD_LDS16(ga1 + k0, la1);
        GLOAD_LDS16(gb0 + k0, lb0);
        GLOAD_LDS16(gb1 + k0, lb1);
        __syncthreads();
        #pragma unroll
        for (int kb = 0; kb < 2; kb++) {
            short8 af[2], bfr[2];
            #pragma unroll
            for (int t = 0; t < 2; t++) {
                int m = ma0 + t * 16 + fm;
                int pa = (kb * 4 + q) ^ (m & 7);
                af[t] = *(const short8*)&As[m][pa * 8];
                int n = na0 + t * 16 + fm;
                int pb = (kb * 4 + q) ^ (n & 7);
                bfr[t] = *(const short8*)&Bs[n][pb * 8];
            }
            #pragma unroll
            for (int i = 0; i < 2; i++)
                #pragma unroll
                for (int j = 0; j < 2; j++)
                    acc[i][j] = __builtin_amdgcn_mfma_f32_16x16x32_bf16(af[i], bfr[j], acc[i][j], 0, 0, 0);
        }
        __syncthreads();
    }
    #pragma unroll
    for (int i = 0; i < 2; i++)
        #pragma unroll
        for (int j = 0; j < 2; j++) {
            int row = m0 + ma0 + i * 16 + q * 4;
            int col = n0 + na0 + j * 16 + fm;
            #pragma unroll
            for (int t = 0; t < 4; t++)
                C[(size_t)(row + t) * ldc + col] = acc[i][j][t];
        }
}

// ---------- same GEMM, but writes last-128 out rows directly + captures rbuf ----------
__global__ __launch_bounds__(256) void gemm_out(const ushort_t* __restrict__ A,
                                                const ushort_t* __restrict__ W,
                                                float* __restrict__ out,
                                                float* __restrict__ rbuf) {
    __shared__ ushort_t As[64][64];
    __shared__ ushort_t Bs[64][64];
    int tid = threadIdx.x;
    int lane = tid & 63, w = tid >> 6;
    int m0 = blockIdx.y * 64, n0 = blockIdx.x * 64;
    int f0 = tid, f1 = tid + 256;
    int r0 = f0 >> 3, g0 = (f0 & 7) ^ (r0 & 7);
    int r1 = f1 >> 3, g1 = (f1 & 7) ^ (r1 & 7);
    const ushort_t* ga0 = A + (size_t)(m0 + r0) * KDIM + g0 * 8;
    const ushort_t* ga1 = A + (size_t)(m0 + r1) * KDIM + g1 * 8;
    const ushort_t* gb0 = W + (size_t)(n0 + r0) * KDIM + g0 * 8;
    const ushort_t* gb1 = W + (size_t)(n0 + r1) * KDIM + g1 * 8;
    char* la0 = (char*)As + f0 * 16;
    char* la1 = (char*)As + f1 * 16;
    char* lb0 = (char*)Bs + f0 * 16;
    char* lb1 = (char*)Bs + f1 * 16;
    int fm = lane & 15, q = lane >> 4;
    int wr = w >> 1, wc = w & 1;
    int ma0 = wr * 32, na0 = wc * 32;
    floatx4 acc[2][2] = {};
    for (int k0 = 0; k0 < KDIM; k0 += 64) {
        GLOAD_LDS16(ga0 + k0, la0);
        GLOAD_LDS16(ga1 + k0, la1);
        GLOAD_LDS16(gb0 + k0, lb0);
        GLOAD_LDS16(gb1 + k0, lb1);
        __syncthreads();
        #pragma unroll
        for (int kb = 0; kb < 2; kb++) {
            short8 af[2], bfr[2];
            #pragma unroll
            for (int t = 0; t < 2; t++) {
                int m = ma0 + t * 16 + fm;
                int pa = (kb * 4 + q) ^ (m & 7);
                af[t] = *(const short8*)&As[m][pa * 8];
                int n = na0 + t * 16 + fm;
                int pb = (kb * 4 + q) ^ (n & 7);
                bfr[t] = *(const short8*)&Bs[n][pb * 8];
            }
            #pragma unroll
            for (int i = 0; i < 2; i++)
                #pragma unroll
                for (int j = 0; j < 2; j++)
                    acc[i][j] = __builtin_amdgcn_mfma_f32_16x16x32_bf16(af[i], bfr[j], acc[i][j], 0, 0, 0);
        }
        __syncthreads();
    }
    #pragma unroll
    for (int i = 0; i < 2; i++)
        #pragma unroll
        for (int j = 0; j < 2; j++) {
            int rowg = m0 + ma0 + i * 16 + q * 4;
            int col = n0 + na0 + j * 16 + fm;
            #pragma unroll
            for (int t = 0; t < 4; t++) {
                int m = rowg + t;
                int b = m >> 7, p = m & 127;
                float val = acc[i][j][t];
                out[(size_t)(b * S_ + CSTART + p) * H_ + col] = val;
                if (p == 0) rbuf[b * H_ + col] = val;
            }
        }
}

// ---------- MFMA attention: block = (b,h), 8 waves; softmax in registers ----------
// LDS: Qs[128][72] / Ksh[128][72] bf16 (overlaid later by Pb[128][136]),
//      linv[128] f32, amk[128] int, Vt[64][136] bf16 (V transposed). 55296 B.
__global__ __launch_bounds__(512) void attn(const float* __restrict__ QKV,
                                            const int* __restrict__ amask,
                                            ushort_t* __restrict__ AO) {
    __shared__ __align__(16) char smem[55296];
    ushort_t* Qs  = (ushort_t*)(smem);             // stride 72
    ushort_t* Ksh = (ushort_t*)(smem + 18432);     // stride 72
    ushort_t* Pb  = (ushort_t*)(smem);             // overlay, stride 136
    float*    linv = (float*)(smem + 36864);
    int*      amk  = (int*)(smem + 37376);
    ushort_t* Vt   = (ushort_t*)(smem + 37888);    // stride 136

    int b = blockIdx.x >> 4;
    int h = blockIdx.x & 15;
    int tid = threadIdx.x;
    // ---- stage Q, K (row-major bf16), V transposed, amask ----
    {
        int r = tid >> 2, ch = tid & 3;   // r 0..127, ch*16 dims
        size_t base = (size_t)(b * CTX + r) * 3072 + h * 64 + ch * 16;
        const float4* qp = (const float4*)(QKV + base);
        const float4* kp = (const float4*)(QKV + base + 1024);
        const float4* vp = (const float4*)(QKV + base + 2048);
        *(uint4*)(Qs  + r * 72 + ch * 16)     = pack8(qp[0], qp[1]);
        *(uint4*)(Qs  + r * 72 + ch * 16 + 8) = pack8(qp[2], qp[3]);
        *(uint4*)(Ksh + r * 72 + ch * 16)     = pack8(kp[0], kp[1]);
        *(uint4*)(Ksh + r * 72 + ch * 16 + 8) = pack8(kp[2], kp[3]);
        float vv[16];
        float4 v0 = vp[0], v1 = vp[1], v2 = vp[2], v3 = vp[3];
        vv[0]=v0.x; vv[1]=v0.y; vv[2]=v0.z; vv[3]=v0.w;
        vv[4]=v1.x; vv[5]=v1.y; vv[6]=v1.z; vv[7]=v1.w;
        vv[8]=v2.x; vv[9]=v2.y; vv[10]=v2.z; vv[11]=v2.w;
        vv[12]=v3.x; vv[13]=v3.y; vv[14]=v3.z; vv[15]=v3.w;
        #pragma unroll
        for (int i = 0; i < 16; i++)
            Vt[(ch * 16 + i) * 136 + r] = f2bf(vv[i]);   // Vt[d][c]
        if (tid < 128) amk[tid] = amask[b * S_ + CSTART + tid];
    }
    __syncthreads();

    int w = tid >> 6, lane = tid & 63;
    int qt = w;                         // this wave's 16-row strip
    int fm = lane & 15, quad = lane >> 4;

    // ---- S = Q K^T (causal tiles only) ----
    short8 af[2];
    #pragma unroll
    for (int kb = 0; kb < 2; kb++)
        af[kb] = *(const short8*)(Qs + (qt * 16 + fm) * 72 + kb * 32 + quad * 8);
    floatx4 acc[8] = {};
    for (int ct = 0; ct <= qt; ct++) {
        #pragma unroll
        for (int kb = 0; kb < 2; kb++) {
            short8 bfr = *(const short8*)(Ksh + (ct * 16 + fm) * 72 + kb * 32 + quad * 8);
            acc[ct] = __builtin_amdgcn_mfma_f32_16x16x32_bf16(af[kb], bfr, acc[ct], 0, 0, 0);
        }
    }
    // ---- softmax in registers (rows = qt*16 + quad*4 + t, cols on 16-lane groups) ----
    int myamk[8];
    #pragma unroll
    for (int ct = 0; ct < 8; ct++) myamk[ct] = amk[ct * 16 + fm];
    float mx[4], ls[4];
    #pragma unroll
    for (int t = 0; t < 4; t++) {
        int row = qt * 16 + quad * 4 + t;
        float m = -INFINITY;
        #pragma unroll
        for (int ct = 0; ct < 8; ct++) {
            int col = ct * 16 + fm;
            float s = acc[ct][t] * 0.125f;
            bool valid = (ct <= qt) && (col <= row) && (myamk[ct] != 0);
            if (valid) m = fmaxf(m, s);
        }
        #pragma unroll
        for (int off = 8; off >= 1; off >>= 1) m = fmaxf(m, __shfl_xor(m, off, 64));
        float l = 0.f;
        #pragma unroll
        for (int ct = 0; ct < 8; ct++) {
            int col = ct * 16 + fm;
            float s = acc[ct][t] * 0.125f;
            bool valid = (ct <= qt) && (col <= row) && (myamk[ct] != 0);
            float p = valid ? __expf(s - m) : 0.f;
            acc[ct][t] = p;
            l += p;
        }
        #pragma unroll
        for (int off = 8; off >= 1; off >>= 1) l += __shfl_xor(l, off, 64);
        mx[t] = m; ls[t] = l;
    }
    __syncthreads();   // all QK^T LDS reads done; Pb overlays Qs/Ksh from here
    // ---- write P (bf16, A-layout rows) + linv ----
    #pragma unroll
    for (int t = 0; t < 4; t++) {
        int row = qt * 16 + quad * 4 + t;
        #pragma unroll
        for (int ct = 0; ct < 8; ct++)
            Pb[row * 136 + ct * 16 + fm] = f2bf(acc[ct][t]);
        if (fm == 0) linv[row] = 1.f / ls[t];
    }
    // ---- O = P V  (K-range limited by causality) ----
    int kmax = (qt >> 1) + 1;           // number of 32-wide k blocks
    floatx4 oacc[4] = {};
    for (int kb = 0; kb < kmax; kb++) {
        short8 paf = *(const short8*)(Pb + (qt * 16 + fm) * 136 + kb * 32 + quad * 8);
        #pragma unroll
        for (int dt = 0; dt < 4; dt++) {
            short8 vbf = *(const short8*)(Vt + (dt * 16 + fm) * 136 + kb * 32 + quad * 8);
            oacc[dt] = __builtin_amdgcn_mfma_f32_16x16x32_bf16(paf, vbf, oacc[dt], 0, 0, 0);
        }
    }
    #pragma unroll
    for (int t = 0; t < 4; t++) {
        int row = qt * 16 + quad * 4 + t;
        float inv = linv[row];
        #pragma unroll
        for (int dt = 0; dt < 4; dt++)
            AO[(size_t)(b * CTX + row) * H_ + h * 64 + dt * 16 + fm] = f2bf(oacc[dt][t] * inv);
    }
}

// ---------- broadcast rows p < CSTART from rbuf ----------
__global__ __launch_bounds__(256) void write_bcast(const float* __restrict__ rbuf,
                                                   float* __restrict__ out) {
    size_t idx = (size_t)blockIdx.x * 256 + threadIdx.x;   // 4*3968*256 float4
    int b   = (int)(idx / (CSTART * 256));
    int rem = (int)(idx % (CSTART * 256));
    int p   = rem >> 8;
    int c4  = rem & 255;
    float4 v = ((const float4*)(rbuf + (size_t)b * H_))[c4];
    ((float4*)(out + (size_t)(b * S_ + p) * H_))[c4] = v;
}

extern "C" void kernel_launch(void* const* d_in, const int* in_sizes, int n_in,
                              void* d_out, int out_size, void* d_ws, size_t ws_size,
                              hipStream_t stream) {
    const float* inputs = (const float*)d_in[0];
    const int*   amask  = (const int*)d_in[1];
    const float* Wq     = (const float*)d_in[2];
    const float* Wk     = (const float*)d_in[3];
    const float* Wv     = (const float*)d_in[4];
    const float* Wo     = (const float*)d_in[5];
    float* out = (float*)d_out;

    char* ws = (char*)d_ws;
    ushort_t* Xs   = (ushort_t*)(ws);                 // 1 MB
    ushort_t* Wbf  = (ushort_t*)(ws + (1u << 20));    // 8 MB (Wq|Wk|Wv|Wo)
    float*    QKV  = (float*)(ws + (9u << 20));       // 6 MB [512][3072]
    ushort_t* AObf = (ushort_t*)(ws + (15u << 20));   // 1 MB [512][1024]
    float*    rbuf = (float*)(ws + (16u << 20));      // 16 KB [4][1024]

    prep<<<2304, 256, 0, stream>>>(inputs, Wq, Wk, Wv, Wo, Wbf, Xs);

    dim3 gq(3072 / 64, 512 / 64);
    gemm_bf16<<<gq, 256, 0, stream>>>(Xs, Wbf, QKV, 3072);

    attn<<<64, 512, 0, stream>>>(QKV, amask, AObf);

    dim3 go(1024 / 64, 512 / 64);
    gemm_out<<<go, 256, 0, stream>>>(AObf, Wbf + (size_t)3072 * 1024, out, rbuf);

    write_bcast<<<(B_ * CSTART * 256) / 256, 256, 0, stream>>>(rbuf, out);
}